// Round 7
// baseline (157.426 us; speedup 1.0000x reference)
//
#include <hip/hip_runtime.h>

// Morphological max-plus dilation, 'same' padding, K=5.
// out[b,o,y,x] = max_{c,i,j} f[b,c,y+i-2,x+j-2] + h[o,c,i,j]
// f(8,32,96,96) fp32, h(32,32,5,5) fp32, out(8,32,96,96) fp32.
//
// R7 = R6 + TLP: in-block c-split widened to CS=4 (8 c's per group),
// 384-thr blocks (6 waves) x 768 blocks = 18 waves/CU (was 9). Keeps the
// register double-buffer over c. Rationale: real VALU busy is only ~26 us
// (VALUBusy overreports 2x on gfx950 -- gfx94x SIMD-16 formula); we are
// ~73% stalled and R3 (TLP alone) / R6 (ILP alone) each helped a little;
// this combines them. VGPR must stay <=113 for 18 waves/CU (R6: 112).
//  - packed-fp16 math (absmax 0.031 << 0.1 threshold)
//  - f pre-padded in d_ws as DUPLICATED half2 (v,v) dwords with NEG halo
//  - YR=2 rows/thread, 6 row-windows (12 dwordx4) per c
//  - NO __launch_bounds__ min-waves arg (R5 spill lesson)

#define B_ 8
#define C_ 32
#define O_ 32
#define H_ 96
#define W_ 96
#define K_ 5

#define TX_ 24             // threads along x; 24*4 = 96 = W
#define RT_ 4              // row-threads per group
#define CS_ 4              // in-block c-split groups
#define TY_ (RT_ * CS_)    // 16
#define NT_ (TX_ * TY_)    // 384 threads = 6 waves
#define XR_ 4              // x outputs per thread
#define YR_ 2              // y outputs per thread
#define OP_ 2              // half2 o-pairs per thread
#define OB_ (OP_ * 2)      // 4 o-channels per block
#define CG_ (C_ / CS_)     // 8 c's per group
#define WR_ (YR_ + K_ - 1) // 6 window rows per thread

// padded f: [b][c][PH][PW] dwords; row = y+2 (0..99), col = x+2 (pad to 104)
#define PH_ 100
#define PW_ 104
#define PLSZ_ (PH_ * PW_)

#define NEGF (-30000.0f)

typedef _Float16 h2 __attribute__((ext_vector_type(2)));

static __device__ __forceinline__ h2 h2b(unsigned u) {
    return __builtin_bit_cast(h2, u);
}
static __device__ __forceinline__ unsigned bh2(h2 v) {
    return __builtin_bit_cast(unsigned, v);
}

// ---------------- pre-pad: f fp32 -> duplicated half2 with NEG halo ----------
__global__ __launch_bounds__(256)
void prepad_kernel(const float* __restrict__ f, unsigned* __restrict__ fpad) {
    const int idx = blockIdx.x * 256 + threadIdx.x;
    const int c = blockIdx.y;
    const int b = blockIdx.z;
    if (idx >= PLSZ_) return;
    const int row = idx / PW_;
    const int col = idx - row * PW_;
    const int y = row - 2;
    const int x = col - 2;
    float v = NEGF;
    if ((unsigned)y < H_ && (unsigned)x < W_)
        v = f[((size_t)(b * C_ + c) * H_ + y) * W_ + x];
    _Float16 hv = (_Float16)v;
    h2 d; d.x = hv; d.y = hv;
    fpad[(size_t)(b * C_ + c) * PLSZ_ + idx] = bh2(d);
}

// ---------------- helpers ----------------------------------------------------
__device__ __forceinline__ void load_win(const unsigned* __restrict__ base,
                                         h2 w[WR_][8]) {
#pragma unroll
    for (int t = 0; t < WR_; ++t) {
        const uint4* p = (const uint4*)(base + t * PW_);
        uint4 a = p[0];
        uint4 b = p[1];
        w[t][0] = h2b(a.x); w[t][1] = h2b(a.y); w[t][2] = h2b(a.z); w[t][3] = h2b(a.w);
        w[t][4] = h2b(b.x); w[t][5] = h2b(b.y); w[t][6] = h2b(b.z); w[t][7] = h2b(b.w);
    }
}

__device__ __forceinline__ void load_win_direct(const float* __restrict__ fc,
                                                int y0r, int x0, h2 w[WR_][8]) {
#pragma unroll
    for (int t = 0; t < WR_; ++t) {
        const int yy = y0r + t - 2;
        const bool yok = (unsigned)yy < H_;
        const float* frow = fc + (size_t)(yok ? yy : 0) * W_;
#pragma unroll
        for (int q = 0; q < 8; ++q) {
            int xc = x0 - 2 + q;
            bool ok = yok && ((unsigned)xc < W_);
            float v = frow[ok ? xc : 0];
            v = ok ? v : NEGF;
            _Float16 hv = (_Float16)v;
            h2 d; d.x = hv; d.y = hv;
            w[t][q] = d;
        }
    }
}

__device__ __forceinline__ void do_math(const unsigned hsrow[K_][K_][OP_],
                                        const h2 w[WR_][8],
                                        h2 acc[YR_][OP_][XR_]) {
#pragma unroll
    for (int i = 0; i < K_; ++i) {
#pragma unroll
        for (int j = 0; j < K_; ++j) {
            uint2 hb = *(const uint2*)&hsrow[i][j][0];   // broadcast b64, aligned
            h2 h0 = h2b(hb.x);
            h2 h1 = h2b(hb.y);
#pragma unroll
            for (int xx = 0; xx < XR_; ++xx) {
                h2 f0 = w[i][xx + j];       // output row 0
                acc[0][0][xx] = __builtin_elementwise_max(acc[0][0][xx], f0 + h0);
                acc[0][1][xx] = __builtin_elementwise_max(acc[0][1][xx], f0 + h1);
                h2 f1 = w[i + 1][xx + j];   // output row 1
                acc[1][0][xx] = __builtin_elementwise_max(acc[1][0][xx], f1 + h0);
                acc[1][1][xx] = __builtin_elementwise_max(acc[1][1][xx], f1 + h1);
            }
        }
    }
}

// ---------------- main kernel ------------------------------------------------
template <bool PADDED>
__global__ __launch_bounds__(NT_)
void dilate_main(const unsigned* __restrict__ fpad, const float* __restrict__ f,
                 const float* __restrict__ h, float* __restrict__ out) {
    const int tx  = threadIdx.x;           // 0..23
    const int ty  = threadIdx.y;           // 0..15
    const int tid = ty * TX_ + tx;         // 0..383
    const int ry  = ty & (RT_ - 1);        // row-thread 0..3
    const int g   = ty >> 2;               // c-split group 0..3

    const int ytile = blockIdx.x;          // 0..11
    const int og    = blockIdx.y;          // 0..7
    const int b     = blockIdx.z;          // 0..7
    const int y0 = ytile * (RT_ * YR_);    // 8 rows per block
    const int o0 = og * OB_;
    const int x0 = XR_ * tx;               // 0..92
    const int yb = y0 + YR_ * ry;          // this thread's first output row

    __shared__ unsigned hs[C_][K_][K_][OP_];                        // 6400 B
    __shared__ unsigned comb[CS_ - 1][YR_ * OP_ * XR_][RT_ * TX_];  // 18432 B

    // stage h: half2(h[o0+2op], h[o0+2op+1]) per (c,i,j,op)
    for (int idx = tid; idx < C_ * K_ * K_ * OP_; idx += NT_) {
        int c  = idx / (K_ * K_ * OP_);
        int rr = idx - c * (K_ * K_ * OP_);
        int ij = rr / OP_;
        int op = rr - ij * OP_;
        int o  = o0 + 2 * op;
        float h0 = h[((size_t)o * C_ + c) * (K_ * K_) + ij];
        float h1 = h[((size_t)(o + 1) * C_ + c) * (K_ * K_) + ij];
        h2 p; p.x = (_Float16)h0; p.y = (_Float16)h1;
        hs[c][ij / K_][ij - (ij / K_) * K_][op] = bh2(p);
    }
    __syncthreads();

    h2 acc[YR_][OP_][XR_];
    {
        h2 neg; neg.x = (_Float16)NEGF; neg.y = (_Float16)NEGF;
#pragma unroll
        for (int r = 0; r < YR_; ++r)
#pragma unroll
            for (int op = 0; op < OP_; ++op)
#pragma unroll
                for (int xx = 0; xx < XR_; ++xx) acc[r][op][xx] = neg;
    }

    const int c0 = g * CG_;
    h2 wA[WR_][8], wB[WR_][8];

    if (PADDED) {
        const unsigned* p = fpad + (size_t)(b * C_ + c0) * PLSZ_ + yb * PW_ + x0;
        load_win(p, wA);
        for (int cc = 0; cc < CG_; cc += 2) {
            load_win(p + (size_t)(cc + 1) * PLSZ_, wB);
            do_math(hs[c0 + cc], wA, acc);
            if (cc + 2 < CG_) load_win(p + (size_t)(cc + 2) * PLSZ_, wA);
            do_math(hs[c0 + cc + 1], wB, acc);
        }
    } else {
        const float* fb = f + (size_t)(b * C_ + c0) * (H_ * W_);
        load_win_direct(fb, yb, x0, wA);
        for (int cc = 0; cc < CG_; cc += 2) {
            load_win_direct(fb + (size_t)(cc + 1) * (H_ * W_), yb, x0, wB);
            do_math(hs[c0 + cc], wA, acc);
            if (cc + 2 < CG_)
                load_win_direct(fb + (size_t)(cc + 2) * (H_ * W_), yb, x0, wA);
            do_math(hs[c0 + cc + 1], wB, acc);
        }
    }

    // ---- combine the four c-groups via LDS (lane-contiguous, conflict-free) -
    const int t96 = ry * TX_ + tx;   // 0..95 within group
    if (g > 0) {
#pragma unroll
        for (int r = 0; r < YR_; ++r)
#pragma unroll
            for (int op = 0; op < OP_; ++op)
#pragma unroll
                for (int xx = 0; xx < XR_; ++xx)
                    comb[g - 1][(r * OP_ + op) * XR_ + xx][t96] =
                        bh2(acc[r][op][xx]);
    }
    __syncthreads();
    if (g == 0) {
#pragma unroll
        for (int r = 0; r < YR_; ++r)
#pragma unroll
            for (int op = 0; op < OP_; ++op)
#pragma unroll
                for (int xx = 0; xx < XR_; ++xx) {
                    const int row = (r * OP_ + op) * XR_ + xx;
                    h2 v0 = h2b(comb[0][row][t96]);
                    h2 v1 = h2b(comb[1][row][t96]);
                    h2 v2 = h2b(comb[2][row][t96]);
                    h2 m = __builtin_elementwise_max(v0, v1);
                    m = __builtin_elementwise_max(m, v2);
                    acc[r][op][xx] = __builtin_elementwise_max(acc[r][op][xx], m);
                }

        // epilogue: unpack to fp32, coalesced float4 per (o, row)
#pragma unroll
        for (int r = 0; r < YR_; ++r) {
            const int y = yb + r;
#pragma unroll
            for (int op = 0; op < OP_; ++op) {
                const int o = o0 + 2 * op;
                float4 lo = make_float4((float)acc[r][op][0].x, (float)acc[r][op][1].x,
                                        (float)acc[r][op][2].x, (float)acc[r][op][3].x);
                float4 hi = make_float4((float)acc[r][op][0].y, (float)acc[r][op][1].y,
                                        (float)acc[r][op][2].y, (float)acc[r][op][3].y);
                *(float4*)&out[(((size_t)b * O_ + o)     * H_ + y) * W_ + x0] = lo;
                *(float4*)&out[(((size_t)b * O_ + o + 1) * H_ + y) * W_ + x0] = hi;
            }
        }
    }
}

extern "C" void kernel_launch(void* const* d_in, const int* in_sizes, int n_in,
                              void* d_out, int out_size, void* d_ws, size_t ws_size,
                              hipStream_t stream) {
    const float* f = (const float*)d_in[0];
    const float* h = (const float*)d_in[1];
    float* out = (float*)d_out;

    dim3 mgrid(H_ / (RT_ * YR_), O_ / OB_, B_);   // (12, 8, 8) = 768 blocks
    dim3 mblock(TX_, TY_);                        // 384 threads = 6 waves

    const size_t need = (size_t)B_ * C_ * PLSZ_ * sizeof(unsigned);  // ~10.7 MB
    if (ws_size >= need) {
        unsigned* fpad = (unsigned*)d_ws;
        dim3 pgrid((PLSZ_ + 255) / 256, C_, B_);
        hipLaunchKernelGGL(prepad_kernel, pgrid, dim3(256), 0, stream, f, fpad);
        hipLaunchKernelGGL((dilate_main<true>), mgrid, mblock, 0, stream,
                           fpad, f, h, out);
    } else {
        hipLaunchKernelGGL((dilate_main<false>), mgrid, mblock, 0, stream,
                           (const unsigned*)nullptr, f, h, out);
    }
}

// Round 8
// 144.836 us; speedup vs baseline: 1.0869x; 1.0869x over previous
//
#include <hip/hip_runtime.h>

// Morphological max-plus dilation, 'same' padding, K=5.
// out[b,o,y,x] = max_{c,i,j} f[b,c,y+i-2,x+j-2] + h[o,c,i,j]
// f(8,32,96,96) fp32, h(32,32,5,5) fp32, out(8,32,96,96) fp32.
//
// R8 = R3's thin low-VGPR structure (36 VGPR, no reg-db, no row-blocking)
// with occupancy pushed: RT 8->4 rows/block, CS 2->4 c-split groups.
// 1536 blocks x 6 waves = 9216 waves = 36/CU nominal (~30 resident).
// Cross-round evidence (R2/R3/R6/R7): dur scales with resident waves/SIMD,
// ILP tricks were neutral and cost VGPRs. TLP with tiny threads is the lever.
//  - packed-fp16 math (absmax 0.031 << 0.1 threshold)
//  - f pre-padded in d_ws as DUPLICATED half2 (v,v) dwords with NEG halo:
//    every window access = one aligned dword, zero repack
//  - NO __launch_bounds__ min-waves arg (R5 spill lesson); VGPR must stay
//    modest on its own (R3 measured 36 with identical inner code).

#define B_ 8
#define C_ 32
#define O_ 32
#define H_ 96
#define W_ 96
#define K_ 5

#define TX_ 24             // threads along x; 24*4 = 96 = W
#define RT_ 4              // row-threads per group (4 output rows per block)
#define CS_ 4              // in-block c-split groups
#define TY_ (RT_ * CS_)    // 16
#define NT_ (TX_ * TY_)    // 384 threads = 6 waves
#define XR_ 4              // x outputs per thread
#define OP_ 2              // half2 o-pairs per thread
#define OB_ (OP_ * 2)      // 4 o-channels per block
#define CG_ (C_ / CS_)     // 8 c's per group

// padded f: [b][c][PH][PW] dwords; row = y+2 (0..99), col = x+2 (pad to 104)
#define PH_ 100
#define PW_ 104
#define PLSZ_ (PH_ * PW_)

#define NEGF (-30000.0f)

typedef _Float16 h2 __attribute__((ext_vector_type(2)));

static __device__ __forceinline__ h2 h2b(unsigned u) {
    return __builtin_bit_cast(h2, u);
}
static __device__ __forceinline__ unsigned bh2(h2 v) {
    return __builtin_bit_cast(unsigned, v);
}

// ---------------- pre-pad: f fp32 -> duplicated half2 with NEG halo ----------
__global__ __launch_bounds__(256)
void prepad_kernel(const float* __restrict__ f, unsigned* __restrict__ fpad) {
    const int idx = blockIdx.x * 256 + threadIdx.x;
    const int c = blockIdx.y;
    const int b = blockIdx.z;
    if (idx >= PLSZ_) return;
    const int row = idx / PW_;
    const int col = idx - row * PW_;
    const int y = row - 2;
    const int x = col - 2;
    float v = NEGF;
    if ((unsigned)y < H_ && (unsigned)x < W_)
        v = f[((size_t)(b * C_ + c) * H_ + y) * W_ + x];
    _Float16 hv = (_Float16)v;
    h2 d; d.x = hv; d.y = hv;
    fpad[(size_t)(b * C_ + c) * PLSZ_ + idx] = bh2(d);
}

// ---------------- main kernel ------------------------------------------------
template <bool PADDED>
__global__ __launch_bounds__(NT_)
void dilate_main(const unsigned* __restrict__ fpad, const float* __restrict__ f,
                 const float* __restrict__ h, float* __restrict__ out) {
    const int tx  = threadIdx.x;           // 0..23
    const int ty  = threadIdx.y;           // 0..15
    const int tid = ty * TX_ + tx;         // 0..383
    const int ry  = ty & (RT_ - 1);        // row-thread 0..3
    const int g   = ty >> 2;               // c-split group 0..3

    const int ytile = blockIdx.x;          // 0..23
    const int og    = blockIdx.y;          // 0..7
    const int b     = blockIdx.z;          // 0..7
    const int y0 = ytile * RT_;            // 4 rows per block
    const int o0 = og * OB_;
    const int x0 = XR_ * tx;               // 0..92
    const int yb = y0 + ry;                // this thread's output row

    __shared__ unsigned hs[C_][K_][K_][OP_];                  // 6400 B
    __shared__ unsigned comb[CS_ - 1][OP_ * XR_][RT_ * TX_];  // 3*8*96*4 = 9216 B

    // stage h: half2(h[o0+2op], h[o0+2op+1]) per (c,i,j,op)
    for (int idx = tid; idx < C_ * K_ * K_ * OP_; idx += NT_) {
        int c  = idx / (K_ * K_ * OP_);
        int rr = idx - c * (K_ * K_ * OP_);
        int ij = rr / OP_;
        int op = rr - ij * OP_;
        int o  = o0 + 2 * op;
        float h0 = h[((size_t)o * C_ + c) * (K_ * K_) + ij];
        float h1 = h[((size_t)(o + 1) * C_ + c) * (K_ * K_) + ij];
        h2 p; p.x = (_Float16)h0; p.y = (_Float16)h1;
        hs[c][ij / K_][ij - (ij / K_) * K_][op] = bh2(p);
    }
    __syncthreads();

    h2 acc[OP_][XR_];
    {
        h2 neg; neg.x = (_Float16)NEGF; neg.y = (_Float16)NEGF;
#pragma unroll
        for (int op = 0; op < OP_; ++op)
#pragma unroll
            for (int xx = 0; xx < XR_; ++xx) acc[op][xx] = neg;
    }

    const int c0 = g * CG_;
    for (int cc = 0; cc < CG_; ++cc) {
        const int c = c0 + cc;
        h2 a[K_][8];   // 5 row-windows of 8 dwords
        if (PADDED) {
            const unsigned* p =
                fpad + (size_t)(b * C_ + c) * PLSZ_ + yb * PW_ + x0;
#pragma unroll
            for (int i = 0; i < K_; ++i) {
                const uint4* q = (const uint4*)(p + i * PW_);
                uint4 w0 = q[0];
                uint4 w1 = q[1];
                a[i][0] = h2b(w0.x); a[i][1] = h2b(w0.y);
                a[i][2] = h2b(w0.z); a[i][3] = h2b(w0.w);
                a[i][4] = h2b(w1.x); a[i][5] = h2b(w1.y);
                a[i][6] = h2b(w1.z); a[i][7] = h2b(w1.w);
            }
        } else {
            const float* fc = f + (size_t)(b * C_ + c) * (H_ * W_);
#pragma unroll
            for (int i = 0; i < K_; ++i) {
                const int yy = yb + i - 2;
                const bool yok = (unsigned)yy < H_;
                const float* frow = fc + (size_t)(yok ? yy : 0) * W_;
#pragma unroll
                for (int q = 0; q < 8; ++q) {
                    int xc = x0 - 2 + q;
                    bool ok = yok && ((unsigned)xc < W_);
                    float v = frow[ok ? xc : 0];
                    v = ok ? v : NEGF;
                    _Float16 hv = (_Float16)v;
                    h2 d; d.x = hv; d.y = hv;
                    a[i][q] = d;
                }
            }
        }

#pragma unroll
        for (int i = 0; i < K_; ++i) {
#pragma unroll
            for (int j = 0; j < K_; ++j) {
                uint2 hb = *(const uint2*)&hs[c][i][j][0];   // broadcast b64
                h2 h0 = h2b(hb.x);
                h2 h1 = h2b(hb.y);
#pragma unroll
                for (int xx = 0; xx < XR_; ++xx) {
                    h2 fv = a[i][xx + j];
                    acc[0][xx] = __builtin_elementwise_max(acc[0][xx], fv + h0);
                    acc[1][xx] = __builtin_elementwise_max(acc[1][xx], fv + h1);
                }
            }
        }
    }

    // ---- combine the four c-groups via LDS (lane-contiguous, conflict-free) -
    const int t96 = ry * TX_ + tx;   // 0..95 within group
    if (g > 0) {
#pragma unroll
        for (int op = 0; op < OP_; ++op)
#pragma unroll
            for (int xx = 0; xx < XR_; ++xx)
                comb[g - 1][op * XR_ + xx][t96] = bh2(acc[op][xx]);
    }
    __syncthreads();
    if (g == 0) {
#pragma unroll
        for (int op = 0; op < OP_; ++op)
#pragma unroll
            for (int xx = 0; xx < XR_; ++xx) {
                const int row = op * XR_ + xx;
                h2 v0 = h2b(comb[0][row][t96]);
                h2 v1 = h2b(comb[1][row][t96]);
                h2 v2 = h2b(comb[2][row][t96]);
                h2 m = __builtin_elementwise_max(v0, v1);
                m = __builtin_elementwise_max(m, v2);
                acc[op][xx] = __builtin_elementwise_max(acc[op][xx], m);
            }

        // epilogue: unpack to fp32, coalesced float4 per o-plane
        const int y = yb;
#pragma unroll
        for (int op = 0; op < OP_; ++op) {
            const int o = o0 + 2 * op;
            float4 lo = make_float4((float)acc[op][0].x, (float)acc[op][1].x,
                                    (float)acc[op][2].x, (float)acc[op][3].x);
            float4 hi = make_float4((float)acc[op][0].y, (float)acc[op][1].y,
                                    (float)acc[op][2].y, (float)acc[op][3].y);
            *(float4*)&out[(((size_t)b * O_ + o)     * H_ + y) * W_ + x0] = lo;
            *(float4*)&out[(((size_t)b * O_ + o + 1) * H_ + y) * W_ + x0] = hi;
        }
    }
}

extern "C" void kernel_launch(void* const* d_in, const int* in_sizes, int n_in,
                              void* d_out, int out_size, void* d_ws, size_t ws_size,
                              hipStream_t stream) {
    const float* f = (const float*)d_in[0];
    const float* h = (const float*)d_in[1];
    float* out = (float*)d_out;

    dim3 mgrid(H_ / RT_, O_ / OB_, B_);   // (24, 8, 8) = 1536 blocks
    dim3 mblock(TX_, TY_);                // 384 threads = 6 waves

    const size_t need = (size_t)B_ * C_ * PLSZ_ * sizeof(unsigned);  // ~10.7 MB
    if (ws_size >= need) {
        unsigned* fpad = (unsigned*)d_ws;
        dim3 pgrid((PLSZ_ + 255) / 256, C_, B_);
        hipLaunchKernelGGL(prepad_kernel, pgrid, dim3(256), 0, stream, f, fpad);
        hipLaunchKernelGGL((dilate_main<true>), mgrid, mblock, 0, stream,
                           fpad, f, h, out);
    } else {
        hipLaunchKernelGGL((dilate_main<false>), mgrid, mblock, 0, stream,
                           (const unsigned*)nullptr, f, h, out);
    }
}